// Round 8
// baseline (182.099 us; speedup 1.0000x reference)
//
#include <hip/hip_runtime.h>
#include <hip/hip_bf16.h>

// compute_pairwise_term, fused + vectorized, 8 px/thread.
// PROBE ROUND: kernel launched TWICE (idempotent) to measure the true
// kernel dispatch time as dur_us_delta vs round 7's single launch.
//
// Identity: with lf = log_sigmoid(x), lb = lf - x,
//   -logaddexp(lf_c+lf_t, lb_c+lb_t) = log_sigmoid(x_c + x_t) - lf_c - lf_t
// OOB taps (zero-padded after log_sigmoid in the reference) give exactly 0.

#define NI 64
#define H_DIM 256
#define W_DIM 256

typedef float f32x4 __attribute__((ext_vector_type(4)));

__device__ __forceinline__ float log_sig(float v) {
    // log_sigmoid(v) = min(v,0) - log1p(exp(-|v|))
    return fminf(v, 0.0f) - __logf(1.0f + __expf(-fabsf(v)));
}

__global__ __launch_bounds__(256) void pairwise_term_v3(
        const float* __restrict__ x, float* __restrict__ out) {
    const int tid = blockIdx.x * blockDim.x + threadIdx.x;  // 1 thread = 8 px
    const int w8 = (tid & 31) << 3;          // 32 col-groups per row
    const int h  = (tid >> 5) & (H_DIM - 1);
    const int n  = tid >> 13;                // total threads = 64*256*32

    const float* img = x + (size_t)n * (H_DIM * W_DIM);

    // Neighborhood: rows {h-2, h, h+2} x cols [w8-4, w8+11] (16 cols loaded,
    // cols c=2..13 i.e. w8-2..w8+9 actually used; edge loads clamped in-range,
    // garbage values masked out by validity below).
    float xr[3][16];
    float lf[3][12];   // log_sig for c = 2..13  (index c-2)
    bool  rowv[3];

#pragma unroll
    for (int r = 0; r < 3; ++r) {
        const int hh = h + 2 * (r - 1);
        rowv[r] = (unsigned)hh < H_DIM;
        const float* rp = img + (size_t)(rowv[r] ? hh : h) * W_DIM;
#pragma unroll
        for (int q = 0; q < 4; ++q) {
            int base = w8 - 4 + 4 * q;
            base = base < 0 ? 0 : (base > W_DIM - 4 ? W_DIM - 4 : base);
            const f32x4 v = *reinterpret_cast<const f32x4*>(rp + base);
            xr[r][4 * q + 0] = v.x; xr[r][4 * q + 1] = v.y;
            xr[r][4 * q + 2] = v.z; xr[r][4 * q + 3] = v.w;
        }
#pragma unroll
        for (int c = 2; c < 14; ++c) lf[r][c - 2] = log_sig(xr[r][c]);
    }

    // taps (row-major kernel order, center removed):
    // t -> (row r in {0,1,2} = {h-2,h,h+2}, dx in {-2,0,2})
    const int tr[8] = {0, 0, 0, 1, 1, 2, 2, 2};
    const int td[8] = {-2, 0, 2, -2, 2, -2, 0, 2};

    float* op = out + ((size_t)n * 8 * H_DIM + h) * W_DIM + w8;

#pragma unroll
    for (int t = 0; t < 8; ++t) {
        const int r  = tr[t];
        const int dx = td[t];
        float res[8];
#pragma unroll
        for (int p = 0; p < 8; ++p) {
            // center col = w8+p (c-index p+4), tap col = w8+p+dx (c-index p+4+dx)
            const float s = xr[1][p + 4] + xr[r][p + 4 + dx];
            const float v = log_sig(s) - lf[1][p + 2] - lf[r][p + 2 + dx];
            const bool ok = rowv[r] && ((unsigned)(w8 + p + dx) < W_DIM);
            res[p] = ok ? v : 0.0f;
        }
        float* tp = op + (size_t)t * (H_DIM * W_DIM);
        f32x4 lo, hi;
        lo.x = res[0]; lo.y = res[1]; lo.z = res[2]; lo.w = res[3];
        hi.x = res[4]; hi.y = res[5]; hi.z = res[6]; hi.w = res[7];
        *reinterpret_cast<f32x4*>(tp)     = lo;
        *reinterpret_cast<f32x4*>(tp + 4) = hi;
    }
}

extern "C" void kernel_launch(void* const* d_in, const int* in_sizes, int n_in,
                              void* d_out, int out_size, void* d_ws, size_t ws_size,
                              hipStream_t stream) {
    const float* x = (const float*)d_in[0];
    float* out = (float*)d_out;
    const int total_threads = NI * H_DIM * (W_DIM / 8);   // 524,288
    const int block = 256;
    const int grid = total_threads / block;               // 2048
    // PROBE: two identical, idempotent launches. kernel_time = dur_us - R7's 152.4.
    pairwise_term_v3<<<grid, block, 0, stream>>>(x, out);
    pairwise_term_v3<<<grid, block, 0, stream>>>(x, out);
}

// Round 9
// 152.775 us; speedup vs baseline: 1.1919x; 1.1919x over previous
//
#include <hip/hip_runtime.h>
#include <hip/hip_bf16.h>

// compute_pairwise_term, fused + vectorized, 8 px/thread. FINAL.
// Input:  mask_logits [N=64, 1, H=256, W=256] fp32
// Output: [N, 8, H, W] fp32; taps row-major, center removed, dilation=2, pad=2.
//
// Identity: with lf = log_sigmoid(x), lb = lf - x,
//   -logaddexp(lf_c+lf_t, lb_c+lb_t) = log_sigmoid(x_c + x_t) - lf_c - lf_t
// OOB taps (zero-padded after log_sigmoid in the reference) give exactly 0.
//
// Measured (R8 double-launch probe): kernel dispatch ~30 µs vs 22.4 µs
// pure-traffic floor (150 MB @ 6.7 TB/s fill-path BW) -> write-BW-bound.

#define NI 64
#define H_DIM 256
#define W_DIM 256

typedef float f32x4 __attribute__((ext_vector_type(4)));

__device__ __forceinline__ float log_sig(float v) {
    // log_sigmoid(v) = min(v,0) - log1p(exp(-|v|))
    return fminf(v, 0.0f) - __logf(1.0f + __expf(-fabsf(v)));
}

__global__ __launch_bounds__(256) void pairwise_term_v3(
        const float* __restrict__ x, float* __restrict__ out) {
    const int tid = blockIdx.x * blockDim.x + threadIdx.x;  // 1 thread = 8 px
    const int w8 = (tid & 31) << 3;          // 32 col-groups per row
    const int h  = (tid >> 5) & (H_DIM - 1);
    const int n  = tid >> 13;                // total threads = 64*256*32

    const float* img = x + (size_t)n * (H_DIM * W_DIM);

    // Neighborhood: rows {h-2, h, h+2} x cols [w8-4, w8+11] (16 cols loaded,
    // cols c=2..13 i.e. w8-2..w8+9 actually used; edge loads clamped in-range,
    // garbage values masked out by validity below).
    float xr[3][16];
    float lf[3][12];   // log_sig for c = 2..13  (index c-2)
    bool  rowv[3];

#pragma unroll
    for (int r = 0; r < 3; ++r) {
        const int hh = h + 2 * (r - 1);
        rowv[r] = (unsigned)hh < H_DIM;
        const float* rp = img + (size_t)(rowv[r] ? hh : h) * W_DIM;
#pragma unroll
        for (int q = 0; q < 4; ++q) {
            int base = w8 - 4 + 4 * q;
            base = base < 0 ? 0 : (base > W_DIM - 4 ? W_DIM - 4 : base);
            const f32x4 v = *reinterpret_cast<const f32x4*>(rp + base);
            xr[r][4 * q + 0] = v.x; xr[r][4 * q + 1] = v.y;
            xr[r][4 * q + 2] = v.z; xr[r][4 * q + 3] = v.w;
        }
#pragma unroll
        for (int c = 2; c < 14; ++c) lf[r][c - 2] = log_sig(xr[r][c]);
    }

    // taps (row-major kernel order, center removed):
    // t -> (row r in {0,1,2} = {h-2,h,h+2}, dx in {-2,0,2})
    const int tr[8] = {0, 0, 0, 1, 1, 2, 2, 2};
    const int td[8] = {-2, 0, 2, -2, 2, -2, 0, 2};

    float* op = out + ((size_t)n * 8 * H_DIM + h) * W_DIM + w8;

#pragma unroll
    for (int t = 0; t < 8; ++t) {
        const int r  = tr[t];
        const int dx = td[t];
        float res[8];
#pragma unroll
        for (int p = 0; p < 8; ++p) {
            // center col = w8+p (c-index p+4), tap col = w8+p+dx (c-index p+4+dx)
            const float s = xr[1][p + 4] + xr[r][p + 4 + dx];
            const float v = log_sig(s) - lf[1][p + 2] - lf[r][p + 2 + dx];
            const bool ok = rowv[r] && ((unsigned)(w8 + p + dx) < W_DIM);
            res[p] = ok ? v : 0.0f;
        }
        float* tp = op + (size_t)t * (H_DIM * W_DIM);
        f32x4 lo, hi;
        lo.x = res[0]; lo.y = res[1]; lo.z = res[2]; lo.w = res[3];
        hi.x = res[4]; hi.y = res[5]; hi.z = res[6]; hi.w = res[7];
        *reinterpret_cast<f32x4*>(tp)     = lo;
        *reinterpret_cast<f32x4*>(tp + 4) = hi;
    }
}

extern "C" void kernel_launch(void* const* d_in, const int* in_sizes, int n_in,
                              void* d_out, int out_size, void* d_ws, size_t ws_size,
                              hipStream_t stream) {
    const float* x = (const float*)d_in[0];
    float* out = (float*)d_out;
    const int total_threads = NI * H_DIM * (W_DIM / 8);   // 524,288
    const int block = 256;
    const int grid = total_threads / block;               // 2048
    pairwise_term_v3<<<grid, block, 0, stream>>>(x, out);
}